// Round 9
// baseline (124.399 us; speedup 1.0000x reference)
//
#include <hip/hip_runtime.h>

#define N 512
#define SLICE (512 * 512)
#define KAPPA2 0.1089f   // 0.33^2
#define GAMMA  1.0f
#define BETA   25.0f

// Wave = full row: lane L owns px [8L, 8L+8). Span s[0..9] covers [8L-1, 8L+8].
// Edges via shuffle; lane 0 / 63 get the Dirichlet zero boundary.
__device__ __forceinline__ void loadspan10(const float* __restrict__ p, int lane,
                                           float s[10]) {
    const float4 A = *reinterpret_cast<const float4*>(p);
    const float4 B = *reinterpret_cast<const float4*>(p + 4);
    s[1] = A.x; s[2] = A.y; s[3] = A.z; s[4] = A.w;
    s[5] = B.x; s[6] = B.y; s[7] = B.z; s[8] = B.w;
    const float lw = __shfl_up(B.w, 1, 64);
    const float rx = __shfl_down(A.x, 1, 64);
    s[0] = (lane == 0)  ? 0.0f : lw;
    s[9] = (lane == 63) ? 0.0f : rx;
}

__device__ __forceinline__ void zero10(float s[10]) {
    #pragma unroll
    for (int j = 0; j < 10; ++j) s[j] = 0.0f;
}

// One stencil row for one slice. TT: 0 = t==0 term (|Ax|^2 + 1.05|x|^2),
// 1 = middle t (|Mx|^2 - 2 xp.Mx + |x|^2), 2 = t==6 (no |x|^2).
template <int TT>
__device__ __forceinline__ float rowq(const float* sm, const float* sc, const float* su,
                                      const float* vxs, const float* vys, const float* xp) {
    float q = 0.0f;
    #pragma unroll
    for (int j = 0; j < 8; ++j) {
        const float c   = sc[j + 1];
        const float uxx = sc[j] + sc[j + 2] - 2.0f * c;
        const float uyy = sm[j + 1] + su[j + 1] - 2.0f * c;
        const float uxy = 0.25f * (su[j + 2] - su[j] - sm[j + 2] + sm[j]);
        const float vx = vxs[j], vy = vys[j];
        const float div = (GAMMA + BETA * vx * vx) * uxx
                        + (2.0f * BETA * vx * vy) * uxy
                        + (GAMMA + BETA * vy * vy) * uyy;
        const float Ax  = KAPPA2 * c - div;
        if (TT == 0) {
            q += Ax * Ax + 1.05f * c * c;
        } else {
            const float Mx = c + Ax;   // DT = 1
            q += Mx * Mx - 2.0f * xp[j] * Mx;
            if (TT == 1) q += c * c;
        }
    }
    return q;
}

// Rolling 4-row strip over slices {T0} (NSL=1) or {T0, T0+1} (NSL=2).
// Upper slice's cross term x_{T0} comes from scA (registers, no load).
// Lower slice's cross term x_{T0-1} is loaded (T0 = 2,4,6); T0 = 0 has none.
template <int T0, int NSL>
__device__ __forceinline__ float strip_q(const float* __restrict__ base, int y0, int lane) {
    constexpr int TTa = (T0 == 0) ? 0 : ((T0 == 6) ? 2 : 1);
    const float* ua = base + (size_t)T0 * SLICE;
    const float* ub = base + (size_t)(T0 + 1) * SLICE;
    const int xo = lane * 8;

    float smA[10], scA[10], suA[10];
    float smB[10], scB[10], suB[10];
    if (y0 > 0) {
        loadspan10(ua + (size_t)(y0 - 1) * N + xo, lane, smA);
        if (NSL == 2) loadspan10(ub + (size_t)(y0 - 1) * N + xo, lane, smB);
    } else {
        zero10(smA);
        if (NSL == 2) zero10(smB);
    }
    loadspan10(ua + (size_t)y0 * N + xo, lane, scA);
    if (NSL == 2) loadspan10(ub + (size_t)y0 * N + xo, lane, scB);

    float q = 0.0f;
    #pragma unroll
    for (int k = 0; k < 4; ++k) {
        const int y = y0 + k;
        const size_t ro = (size_t)y * N + xo;

        if (y + 1 < N) {
            loadspan10(ua + ro + N, lane, suA);
            if (NSL == 2) loadspan10(ub + ro + N, lane, suB);
        } else {
            zero10(suA);
            if (NSL == 2) zero10(suB);
        }

        const float4 vx4a = *reinterpret_cast<const float4*>(base + 7 * SLICE + ro);
        const float4 vx4b = *reinterpret_cast<const float4*>(base + 7 * SLICE + ro + 4);
        const float4 vy4a = *reinterpret_cast<const float4*>(base + 8 * SLICE + ro);
        const float4 vy4b = *reinterpret_cast<const float4*>(base + 8 * SLICE + ro + 4);
        const float vxs[8] = {vx4a.x, vx4a.y, vx4a.z, vx4a.w, vx4b.x, vx4b.y, vx4b.z, vx4b.w};
        const float vys[8] = {vy4a.x, vy4a.y, vy4a.z, vy4a.w, vy4b.x, vy4b.y, vy4b.z, vy4b.w};

        float xpa[8];
        if (T0 > 0) {
            const float* up = base + (size_t)(T0 - 1) * SLICE + ro;
            const float4 XA = *reinterpret_cast<const float4*>(up);
            const float4 XB = *reinterpret_cast<const float4*>(up + 4);
            xpa[0] = XA.x; xpa[1] = XA.y; xpa[2] = XA.z; xpa[3] = XA.w;
            xpa[4] = XB.x; xpa[5] = XB.y; xpa[6] = XB.z; xpa[7] = XB.w;
        } else {
            #pragma unroll
            for (int j = 0; j < 8; ++j) xpa[j] = 0.0f;
        }

        q += rowq<TTa>(smA, scA, suA, vxs, vys, xpa);
        if (NSL == 2)
            q += rowq<1>(smB, scB, suB, vxs, vys, scA + 1);   // xp = x_{T0} row y (regs)

        #pragma unroll
        for (int i = 0; i < 10; ++i) {
            smA[i] = scA[i]; scA[i] = suA[i];
            if (NSL == 2) { smB[i] = scB[i]; scB[i] = suB[i]; }
        }
    }
    return q;
}

// state: [B=8, 9, 512, 512] f32. slices 0..6 = x_t, 7 = vx, 8 = vy.
// Stage 1: 4096 one-wave blocks = 8 b (bid&7 -> XCD-pinned) x 4 t-groups x 128 strips.
__global__ __launch_bounds__(64, 4) void phi_q_stage1(const float* __restrict__ state,
                                                      float* __restrict__ ws) {
    const int bid  = blockIdx.x;     // 4096
    const int b    = bid & 7;
    const int g    = bid >> 3;       // 0..511
    const int tg   = g & 3;          // t-group, round-robin for CU balance
    const int y0   = (g >> 2) * 4;   // strip base row
    const int lane = threadIdx.x;

    const float* base = state + (size_t)b * 9 * SLICE;

    float q;
    if      (tg == 0) q = strip_q<0, 2>(base, y0, lane);
    else if (tg == 1) q = strip_q<2, 2>(base, y0, lane);
    else if (tg == 2) q = strip_q<4, 2>(base, y0, lane);
    else              q = strip_q<6, 1>(base, y0, lane);

    #pragma unroll
    for (int off = 32; off > 0; off >>= 1)
        q += __shfl_down(q, off, 64);

    if (lane == 0) ws[bid] = q;
}

// Stage 2: 8 blocks; block b sums its 512 partials (ws[b + 8k]).
__global__ __launch_bounds__(256) void phi_q_stage2(const float* __restrict__ ws,
                                                    float* __restrict__ out) {
    const int b = blockIdx.x;
    float v = ws[b + 8 * threadIdx.x] + ws[b + 8 * (threadIdx.x + 256)];
    #pragma unroll
    for (int off = 32; off > 0; off >>= 1)
        v += __shfl_down(v, off, 64);

    __shared__ float sred[4];
    const int lane = threadIdx.x & 63;
    const int wid  = threadIdx.x >> 6;
    if (lane == 0) sred[wid] = v;
    __syncthreads();
    if (threadIdx.x == 0) out[b] = sred[0] + sred[1] + sred[2] + sred[3];
}

extern "C" void kernel_launch(void* const* d_in, const int* in_sizes, int n_in,
                              void* d_out, int out_size, void* d_ws, size_t ws_size,
                              hipStream_t stream) {
    const float* state = (const float*)d_in[0];
    float* out = (float*)d_out;
    float* ws  = (float*)d_ws;

    phi_q_stage1<<<4096, 64, 0, stream>>>(state, ws);
    phi_q_stage2<<<8, 256, 0, stream>>>(ws, out);
}

// Round 10
// 37.924 us; speedup vs baseline: 3.2802x; 3.2802x over previous
//
#include <hip/hip_runtime.h>

#define N 512
#define SLICE (512 * 512)
#define KAPPA2 0.1089f   // 0.33^2
#define GAMMA  1.0f
#define BETA   25.0f

// Wave = full row: lane L owns px [8L, 8L+8). Span s[0..9] covers [8L-1, 8L+8].
// Edges via shuffle; lane 0 / 63 get the Dirichlet zero boundary.
__device__ __forceinline__ void loadspan10(const float* __restrict__ p, int lane,
                                           float s[10]) {
    const float4 A = *reinterpret_cast<const float4*>(p);
    const float4 B = *reinterpret_cast<const float4*>(p + 4);
    s[1] = A.x; s[2] = A.y; s[3] = A.z; s[4] = A.w;
    s[5] = B.x; s[6] = B.y; s[7] = B.z; s[8] = B.w;
    const float lw = __shfl_up(B.w, 1, 64);
    const float rx = __shfl_down(A.x, 1, 64);
    s[0] = (lane == 0)  ? 0.0f : lw;
    s[9] = (lane == 63) ? 0.0f : rx;
}

__device__ __forceinline__ void zero10(float s[10]) {
    #pragma unroll
    for (int j = 0; j < 10; ++j) s[j] = 0.0f;
}

// state: [B=8, 9, 512, 512] f32. slices 0..6 = x_t, 7 = vx, 8 = vy.
// q decomposition (per slice t, summed over pixels):
//   t=0: |Ax0|^2 + 1.05|x0|^2;  t=1..5: |Mx_t|^2 - 2 x_{t-1}.Mx_t + |x_t|^2;
//   t=6: |Mx_6|^2 - 2 x_5.Mx_6.
// Branch-free per-pixel form: val = m*c + Ax (m=0 at t=0 -> val=Ax, else Mx),
//   q += val^2 - 2*xp*val + ccoef*c^2, with xp=0 at t=0,
//   ccoef = 1.05 (t=0), 1.0 (t=1..5), 0.0 (t=6).
// Stage 1: one wave per (b, t, 8-row strip), rolling spans down the strip.
// bid = (strip*7 + t)*8 + b: XCD pinned to batch; (strip,t) and (strip,t+1)
// adjacent so slice-t rows are L1/L2-hot when re-read as x_{t-1}.
__global__ __launch_bounds__(64) void phi_q_stage1(const float* __restrict__ state,
                                                   float* __restrict__ ws) {
    const int bid  = blockIdx.x;       // 3584 = 8 * 7 * 64
    const int b    = bid & 7;
    const int g    = bid >> 3;         // strip*7 + t
    const int strip = g / 7;           // scalar magic-div
    const int t    = g - strip * 7;
    const int y0   = strip * 8;
    const int lane = threadIdx.x;
    const int xo   = lane * 8;

    const float* base = state + (size_t)b * 9 * SLICE;
    const float* u    = base + (size_t)t * SLICE;
    const float* vxp  = base + 7 * SLICE;
    const float* vyp  = base + 8 * SLICE;
    const float* xprv = u - SLICE;     // only dereferenced when t > 0

    const float m     = (t == 0) ? 0.0f : 1.0f;
    const float ccoef = (t == 0) ? 1.05f : ((t < 6) ? 1.0f : 0.0f);

    float sm[10], sc[10], su[10];
    if (y0 > 0) loadspan10(u + (size_t)(y0 - 1) * N + xo, lane, sm);
    else        zero10(sm);
    loadspan10(u + (size_t)y0 * N + xo, lane, sc);

    float q = 0.0f;
    #pragma unroll
    for (int k = 0; k < 8; ++k) {
        const int y = y0 + k;
        const size_t ro = (size_t)y * N + xo;

        if (y + 1 < N) loadspan10(u + ro + N, lane, su);
        else           zero10(su);

        const float4 vxA = *reinterpret_cast<const float4*>(vxp + ro);
        const float4 vxB = *reinterpret_cast<const float4*>(vxp + ro + 4);
        const float4 vyA = *reinterpret_cast<const float4*>(vyp + ro);
        const float4 vyB = *reinterpret_cast<const float4*>(vyp + ro + 4);
        const float vxs[8] = {vxA.x, vxA.y, vxA.z, vxA.w, vxB.x, vxB.y, vxB.z, vxB.w};
        const float vys[8] = {vyA.x, vyA.y, vyA.z, vyA.w, vyB.x, vyB.y, vyB.z, vyB.w};

        float xp8[8];
        if (t > 0) {                   // wave-uniform
            const float4 XA = *reinterpret_cast<const float4*>(xprv + ro);
            const float4 XB = *reinterpret_cast<const float4*>(xprv + ro + 4);
            xp8[0] = XA.x; xp8[1] = XA.y; xp8[2] = XA.z; xp8[3] = XA.w;
            xp8[4] = XB.x; xp8[5] = XB.y; xp8[6] = XB.z; xp8[7] = XB.w;
        } else {
            #pragma unroll
            for (int j = 0; j < 8; ++j) xp8[j] = 0.0f;
        }

        #pragma unroll
        for (int j = 0; j < 8; ++j) {
            const float c   = sc[j + 1];
            const float uxx = sc[j] + sc[j + 2] - 2.0f * c;
            const float uyy = sm[j + 1] + su[j + 1] - 2.0f * c;
            const float uxy = 0.25f * (su[j + 2] - su[j] - sm[j + 2] + sm[j]);
            const float vx = vxs[j], vy = vys[j];
            const float div = (GAMMA + BETA * vx * vx) * uxx
                            + (2.0f * BETA * vx * vy) * uxy
                            + (GAMMA + BETA * vy * vy) * uyy;
            const float Ax  = KAPPA2 * c - div;
            const float val = m * c + Ax;          // Ax at t=0, Mx otherwise
            q += val * val - 2.0f * xp8[j] * val + ccoef * c * c;
        }

        #pragma unroll
        for (int i = 0; i < 10; ++i) { sm[i] = sc[i]; sc[i] = su[i]; }
    }

    // wave reduce -> one partial per wave; contiguous per batch for stage 2.
    #pragma unroll
    for (int off = 32; off > 0; off >>= 1)
        q += __shfl_down(q, off, 64);

    if (lane == 0) ws[b * 448 + g] = q;
}

// Stage 2: 8 blocks; block b sums its contiguous 448 partials.
__global__ __launch_bounds__(256) void phi_q_stage2(const float* __restrict__ ws,
                                                    float* __restrict__ out) {
    const int b = blockIdx.x;
    const float* p = ws + b * 448;
    float v = p[threadIdx.x];
    if (threadIdx.x < 192) v += p[256 + threadIdx.x];

    #pragma unroll
    for (int off = 32; off > 0; off >>= 1)
        v += __shfl_down(v, off, 64);

    __shared__ float sred[4];
    const int lane = threadIdx.x & 63;
    const int wid  = threadIdx.x >> 6;
    if (lane == 0) sred[wid] = v;
    __syncthreads();
    if (threadIdx.x == 0) out[b] = sred[0] + sred[1] + sred[2] + sred[3];
}

extern "C" void kernel_launch(void* const* d_in, const int* in_sizes, int n_in,
                              void* d_out, int out_size, void* d_ws, size_t ws_size,
                              hipStream_t stream) {
    const float* state = (const float*)d_in[0];
    float* out = (float*)d_out;
    float* ws  = (float*)d_ws;

    phi_q_stage1<<<3584, 64, 0, stream>>>(state, ws);
    phi_q_stage2<<<8, 256, 0, stream>>>(ws, out);
}

// Round 11
// 21.442 us; speedup vs baseline: 5.8016x; 1.7687x over previous
//
#include <hip/hip_runtime.h>

#define N 512
#define SLICE (512 * 512)
#define KAPPA2 0.1089f   // 0.33^2
#define GAMMA  1.0f
#define BETA   25.0f

// Wave = full row: lane L owns px [8L, 8L+8). Span s[0..9] covers [8L-1, 8L+8].
// Edges via shuffle; lane 0 / 63 get the Dirichlet zero boundary.
__device__ __forceinline__ void loadspan10(const float* __restrict__ p, int lane,
                                           float s[10]) {
    const float4 A = *reinterpret_cast<const float4*>(p);
    const float4 B = *reinterpret_cast<const float4*>(p + 4);
    s[1] = A.x; s[2] = A.y; s[3] = A.z; s[4] = A.w;
    s[5] = B.x; s[6] = B.y; s[7] = B.z; s[8] = B.w;
    const float lw = __shfl_up(B.w, 1, 64);
    const float rx = __shfl_down(A.x, 1, 64);
    s[0] = (lane == 0)  ? 0.0f : lw;
    s[9] = (lane == 63) ? 0.0f : rx;
}

__device__ __forceinline__ void zero10(float s[10]) {
    #pragma unroll
    for (int j = 0; j < 10; ++j) s[j] = 0.0f;
}

// state: [B=8, 9, 512, 512] f32. slices 0..6 = x_t, 7 = vx, 8 = vy.
// q decomposition (per slice t, summed over pixels):
//   t=0: |Ax0|^2 + 1.05|x0|^2;  t=1..5: |Mx_t|^2 - 2 x_{t-1}.Mx_t + |x_t|^2;
//   t=6: |Mx_6|^2 - 2 x_5.Mx_6.
// Branch-free per-pixel: val = m*c + Ax (m=0 -> Ax at t=0, else Mx);
//   q += val^2 - 2*xp*val + ccoef*c^2;  xp = x_{t-1} = previous iteration's
//   center span (REGISTERS — no load); H from vx,vy computed once, reused 7x.
// Stage 1: one wave per (b, y). bid = y*8 + b: default %8 round-robin pins
// batch->XCD; y-neighbor waves (row sharing) temporally adjacent on that XCD.
__global__ __launch_bounds__(64) void phi_q_stage1(const float* __restrict__ state,
                                                   float* __restrict__ ws) {
    const int bid  = blockIdx.x;       // 4096 = 512 * 8
    const int b    = bid & 7;
    const int y    = bid >> 3;
    const int lane = threadIdx.x;
    const int xo   = lane * 8;

    const float* base = state + (size_t)b * 9 * SLICE;
    const size_t ro   = (size_t)y * N + xo;

    const bool ym = (y > 0), yp = (y < N - 1);   // wave-uniform

    // Diffusion tensor for this row's 8 px: computed once, reused for all 7 t.
    float H11[8], H12[8], H22[8];
    {
        const float4 vxA = *reinterpret_cast<const float4*>(base + 7 * SLICE + ro);
        const float4 vxB = *reinterpret_cast<const float4*>(base + 7 * SLICE + ro + 4);
        const float4 vyA = *reinterpret_cast<const float4*>(base + 8 * SLICE + ro);
        const float4 vyB = *reinterpret_cast<const float4*>(base + 8 * SLICE + ro + 4);
        const float vxs[8] = {vxA.x, vxA.y, vxA.z, vxA.w, vxB.x, vxB.y, vxB.z, vxB.w};
        const float vys[8] = {vyA.x, vyA.y, vyA.z, vyA.w, vyB.x, vyB.y, vyB.z, vyB.w};
        #pragma unroll
        for (int j = 0; j < 8; ++j) {
            H11[j] = GAMMA + BETA * vxs[j] * vxs[j];
            H12[j] = 2.0f * BETA * vxs[j] * vys[j];
            H22[j] = GAMMA + BETA * vys[j] * vys[j];
        }
    }

    float xprev[8];
    #pragma unroll
    for (int j = 0; j < 8; ++j) xprev[j] = 0.0f;

    float q = 0.0f;
    float m = 0.0f;            // 0 at t=0 (val=Ax), 1 after (val=Mx)

    #pragma unroll 1           // keep rolled: avoid load hoisting / VGPR blowup
    for (int t = 0; t < 7; ++t) {
        const float* u = base + (size_t)t * SLICE;
        float sm[10], sc[10], su[10];
        loadspan10(u + ro, lane, sc);
        if (ym) loadspan10(u + ro - N, lane, sm);
        else    zero10(sm);
        if (yp) loadspan10(u + ro + N, lane, su);
        else    zero10(su);

        const float ccoef = (t == 0) ? 1.05f : ((t < 6) ? 1.0f : 0.0f);

        #pragma unroll
        for (int j = 0; j < 8; ++j) {
            const float c   = sc[j + 1];
            const float uxx = sc[j] + sc[j + 2] - 2.0f * c;
            const float uyy = sm[j + 1] + su[j + 1] - 2.0f * c;
            const float uxy = 0.25f * (su[j + 2] - su[j] - sm[j + 2] + sm[j]);
            const float div = H11[j] * uxx + H12[j] * uxy + H22[j] * uyy;
            const float Ax  = KAPPA2 * c - div;
            const float val = m * c + Ax;            // Ax at t=0, Mx else
            q += val * val - 2.0f * xprev[j] * val + ccoef * c * c;
            xprev[j] = c;                            // x_t for next iteration
        }
        m = 1.0f;
    }

    // wave reduce -> one partial per wave; ws[b*512 + y] contiguous per batch.
    #pragma unroll
    for (int off = 32; off > 0; off >>= 1)
        q += __shfl_down(q, off, 64);

    if (lane == 0) ws[b * 512 + y] = q;
}

// Stage 2: 8 blocks; block b sums its contiguous 512 partials.
__global__ __launch_bounds__(256) void phi_q_stage2(const float* __restrict__ ws,
                                                    float* __restrict__ out) {
    const int b = blockIdx.x;
    const float* p = ws + b * 512;
    float v = p[threadIdx.x] + p[threadIdx.x + 256];

    #pragma unroll
    for (int off = 32; off > 0; off >>= 1)
        v += __shfl_down(v, off, 64);

    __shared__ float sred[4];
    const int lane = threadIdx.x & 63;
    const int wid  = threadIdx.x >> 6;
    if (lane == 0) sred[wid] = v;
    __syncthreads();
    if (threadIdx.x == 0) out[b] = sred[0] + sred[1] + sred[2] + sred[3];
}

extern "C" void kernel_launch(void* const* d_in, const int* in_sizes, int n_in,
                              void* d_out, int out_size, void* d_ws, size_t ws_size,
                              hipStream_t stream) {
    const float* state = (const float*)d_in[0];
    float* out = (float*)d_out;
    float* ws  = (float*)d_ws;

    phi_q_stage1<<<4096, 64, 0, stream>>>(state, ws);
    phi_q_stage2<<<8, 256, 0, stream>>>(ws, out);
}